// Round 6
// baseline (486.503 us; speedup 1.0000x reference)
//
#include <hip/hip_runtime.h>
#include <hip/hip_bf16.h>
#include <math.h>

typedef unsigned short u16;
typedef __attribute__((ext_vector_type(8))) short short8;   // 8 bf16 (4 VGPRs)
typedef __attribute__((ext_vector_type(4))) float f32x4;

#define N_TOK   8192
#define N_HEADS 4
#define KDIM    512
#define HALFD   256
#define VDIM    512
#define SUBK    512
#define NCAND   16

__device__ __forceinline__ u16 f2bf(float f) {
    unsigned u = __float_as_uint(f);
    u += 0x7fffu + ((u >> 16) & 1u);
    return (u16)(u >> 16);
}

__device__ __forceinline__ unsigned med3u(unsigned a, unsigned b, unsigned c) {
    unsigned d;
    asm("v_med3_u32 %0, %1, %2, %3" : "=v"(d) : "v"(a), "v"(b), "v"(c));
    return d;
}

// ---------------- Kernel A: f32 -> bf16 bits (keys only, tiny) ----------------
__global__ void k_convert(const float* __restrict__ in, u16* __restrict__ out, int n4) {
    int i = blockIdx.x * blockDim.x + threadIdx.x;
    int stride = gridDim.x * blockDim.x;
    for (; i < n4; i += stride) {
        float4 v = ((const float4*)in)[i];
        unsigned a = (unsigned)f2bf(v.x) | ((unsigned)f2bf(v.y) << 16);
        unsigned b = (unsigned)f2bf(v.z) | ((unsigned)f2bf(v.w) << 16);
        ((uint2*)out)[i] = make_uint2(a, b);
    }
}

// ================== Fused kernel: score + select + gather ==================
// grid = N/16 blocks, 256 threads. Block handles tokens [16*nb, 16*nb+16).
// Stage 1: 8 passes (g = h*2+half) of bf16-MFMA scoring + packed-key top-16
//          -> candidates in LDS.
// Stage 2: per token: f64 refine, exact 2-stage top-8, softmax, gather.
__global__ __launch_bounds__(256, 2) void k_fused(
    const float* __restrict__ query,   // [N][2048] f32
    const u16*  __restrict__ kb,       // [2][4][512][256] bf16
    const float* __restrict__ keys,    // [2][4][512][256] f32
    const float* __restrict__ values,  // [262144][512] f32
    float* __restrict__ out)           // [N][512] f32
{
    __shared__ unsigned sc[16 * 513];     // 32.8 KB, reused per pass
    __shared__ int    cnd[8][16][NCAND];  // 8 KB: [group][token][cand]
    __shared__ double rv[8][16];
    __shared__ int    ri[8][16];
    __shared__ double tsv[8][8];
    __shared__ int    tsi[8][8];
    __shared__ double s_comb[32];
    __shared__ int    sgi[32];
    __shared__ float  wsm[32];
    __shared__ float  part[4][512];       // 8 KB gather partials

    const int nb = blockIdx.x;
    const int tid = threadIdx.x;
    const int wave = tid >> 6, l = tid & 63;
    const int lr = l & 15, lk = l >> 4;

    // ---------------- Stage 1: scoring, 8 passes ----------------
    for (int g = 0; g < 8; ++g) {
        const int h = g >> 1, half = g & 1;

        // A fragments: q rows nb*16..+15 for this (h,half), f32->bf16 in reg
        const float* qbase = query + (size_t)(nb * 16 + lr) * (N_HEADS * KDIM)
                           + h * KDIM + half * HALFD + lk * 8;
        short8 a[8];
#pragma unroll
        for (int kf = 0; kf < 8; ++kf) {
            float4 q0 = *(const float4*)(qbase + kf * 32);
            float4 q1 = *(const float4*)(qbase + kf * 32 + 4);
            short8 t;
            t[0] = (short)f2bf(q0.x); t[1] = (short)f2bf(q0.y);
            t[2] = (short)f2bf(q0.z); t[3] = (short)f2bf(q0.w);
            t[4] = (short)f2bf(q1.x); t[5] = (short)f2bf(q1.y);
            t[6] = (short)f2bf(q1.z); t[7] = (short)f2bf(q1.w);
            a[kf] = t;
        }

        const u16* kbase = kb + (size_t)(half * N_HEADS + h) * SUBK * HALFD;
#pragma unroll
        for (int t = 0; t < 8; ++t) {
            const int st = wave * 8 + t;
            const u16* kp = kbase + (size_t)(st * 16 + lr) * HALFD + lk * 8;
            short8 b[8];
#pragma unroll
            for (int kf = 0; kf < 8; ++kf)
                b[kf] = *(const short8*)(kp + kf * 32);
            f32x4 acc = {0.f, 0.f, 0.f, 0.f};
#pragma unroll
            for (int kf = 0; kf < 8; ++kf)
                acc = __builtin_amdgcn_mfma_f32_16x16x32_bf16(a[kf], b[kf], acc, 0, 0, 0);
            // D layout: col = lane&15 (key), row = (lane>>4)*4 + reg (q row)
#pragma unroll
            for (int r = 0; r < 4; ++r) {
                unsigned ub = __float_as_uint(acc[r]);
                unsigned key = ub ^ ((unsigned)((int)ub >> 31) | 0x80000000u);
                key = (key & 0xFFFFFE00u) | (unsigned)(st * 16 + lr);
                sc[(lk * 4 + r) * 513 + st * 16 + lr] = key;
            }
        }
        __syncthreads();

        // per-lane exact top-16 of 32 keys via med3 sorted-insert
        const int row = tid >> 4, sub = tid & 15;
        unsigned tv[NCAND];
#pragma unroll
        for (int j = 0; j < NCAND; ++j) tv[j] = 0u;
        const int base = row * 513 + sub;
#pragma unroll
        for (int t = 0; t < 32; ++t) {
            unsigned v = sc[base + (t << 4)];
#pragma unroll
            for (int j = NCAND - 1; j >= 1; --j)
                tv[j] = med3u(tv[j - 1], tv[j], v);
            tv[0] = (tv[0] > v) ? tv[0] : v;
        }

        // 16-way merge across lanes: umax-shfl + pop (keys unique)
        unsigned keep = 0;
#pragma unroll
        for (int r = 0; r < NCAND; ++r) {
            unsigned w = tv[0];
#pragma unroll
            for (int d = 1; d < 16; d <<= 1) {
                unsigned o = __shfl_xor(w, d, 16);
                w = (o > w) ? o : w;
            }
            if (sub == r) keep = w;
            bool pop = (tv[0] == w);
#pragma unroll
            for (int j = 0; j < NCAND - 1; ++j) tv[j] = pop ? tv[j + 1] : tv[j];
            tv[NCAND - 1] = pop ? 0u : tv[NCAND - 1];
        }
        cnd[g][row][sub] = (int)(keep & 0x1FFu);
        __syncthreads();   // sc reused next pass; cnd visible later
    }

    // ---------------- Stage 2: per-token select + gather ----------------
    for (int tt = 0; tt < 16; ++tt) {
        const int n = nb * 16 + tt;

        // Phase 1: f64 refinement, 2 threads per candidate dot (128 dims each)
        {
            const int dot = tid >> 1, pt = tid & 1;
            const int g = dot >> 4, j = dot & 15;
            const int h = g >> 1, half = g & 1;
            const int sidx = cnd[g][tt][j];
            const float* qrow = query + (size_t)n * (N_HEADS * KDIM) + h * KDIM + half * HALFD + pt * 128;
            const float* krow = keys + ((size_t)(half * N_HEADS + h) * SUBK + sidx) * HALFD + pt * 128;
            double a0 = 0, a1 = 0, a2 = 0, a3 = 0;
#pragma unroll 8
            for (int d = 0; d < 128; d += 4) {
                float4 qv = *(const float4*)(qrow + d);
                float4 kv = *(const float4*)(krow + d);
                a0 = fma((double)qv.x, (double)kv.x, a0);
                a1 = fma((double)qv.y, (double)kv.y, a1);
                a2 = fma((double)qv.z, (double)kv.z, a2);
                a3 = fma((double)qv.w, (double)kv.w, a3);
            }
            double s = (a0 + a1) + (a2 + a3);
            double o = __shfl_xor(s, 1);
            if (pt == 0) { rv[g][j] = s + o; ri[g][j] = sidx; }
        }
        __syncthreads();

        // Phase 2: top-8 of 16 per group (tie -> lowest j)
        if (tid < 128) {
            const int g = tid >> 4, j = tid & 15;
            double v = rv[g][j];
            const int idx = ri[g][j];
            for (int r = 0; r < 8; ++r) {
                double bv = v; int bj = j;
#pragma unroll
                for (int d = 1; d < 16; d <<= 1) {
                    double ov = __shfl_xor(bv, d, 16);
                    int    oj = __shfl_xor(bj, d, 16);
                    if (ov > bv || (ov == bv && oj < bj)) { bv = ov; bj = oj; }
                }
                int widx = __shfl(idx, bj, 16);
                if (j == r) { tsv[g][r] = bv; tsi[g][r] = widx; }
                if (j == bj) v = -1e300;
            }
        }
        __syncthreads();

        // Phase 3: per head (one wave each), top-8 of 64 combos (tie -> lowest f)
        {
            const int h = tid >> 6, f = tid & 63;
            double c = tsv[h * 2][f >> 3] + tsv[h * 2 + 1][f & 7];
            for (int r = 0; r < 8; ++r) {
                double bv = c; int bf = f;
#pragma unroll
                for (int d = 1; d < 64; d <<= 1) {
                    double ov = __shfl_xor(bv, d, 64);
                    int    of = __shfl_xor(bf, d, 64);
                    if (ov > bv || (ov == bv && of < bf)) { bv = ov; bf = of; }
                }
                if (f == r) {
                    s_comb[h * 8 + r] = bv;
                    sgi[h * 8 + r] = tsi[h * 2][bf >> 3] * SUBK + tsi[h * 2 + 1][bf & 7];
                }
                if (f == bf) c = -1e300;
            }
        }
        __syncthreads();

        // Phase 4: joint softmax over 32
        if (tid < 32) {
            const int k = tid;
            double s = s_comb[k];
            double m = s;
#pragma unroll
            for (int d = 1; d < 32; d <<= 1) m = fmax(m, __shfl_xor(m, d, 32));
            float e = expf((float)(s - m));
            float sum = e;
#pragma unroll
            for (int d = 1; d < 32; d <<= 1) sum += __shfl_xor(sum, d, 32);
            wsm[k] = e / sum;
        }
        __syncthreads();

        // Phase 5: gather — wave w reads rows 8w..8w+7 (2 KB each, 1 KB bursts)
        {
            const int w = wave, lane = l;
            float4 acc0 = {0.f, 0.f, 0.f, 0.f};
            float4 acc1 = {0.f, 0.f, 0.f, 0.f};
#pragma unroll
            for (int b = 0; b < 2; ++b) {
                float4 v0[4], v1[4];
#pragma unroll
                for (int r = 0; r < 4; ++r) {
                    const int k = w * 8 + b * 4 + r;
                    const float* vr = values + (size_t)sgi[k] * VDIM;
                    v0[r] = *(const float4*)(vr + lane * 4);
                    v1[r] = *(const float4*)(vr + 256 + lane * 4);
                }
#pragma unroll
                for (int r = 0; r < 4; ++r) {
                    const float wk = wsm[w * 8 + b * 4 + r];
                    acc0.x = fmaf(wk, v0[r].x, acc0.x);
                    acc0.y = fmaf(wk, v0[r].y, acc0.y);
                    acc0.z = fmaf(wk, v0[r].z, acc0.z);
                    acc0.w = fmaf(wk, v0[r].w, acc0.w);
                    acc1.x = fmaf(wk, v1[r].x, acc1.x);
                    acc1.y = fmaf(wk, v1[r].y, acc1.y);
                    acc1.z = fmaf(wk, v1[r].z, acc1.z);
                    acc1.w = fmaf(wk, v1[r].w, acc1.w);
                }
            }
            *(float4*)(&part[w][lane * 4]) = acc0;
            *(float4*)(&part[w][256 + lane * 4]) = acc1;
        }
        __syncthreads();

        // Cross-wave reduction + store
        {
            const int c = tid * 2;
            float s0 = part[0][c]     + part[1][c]     + part[2][c]     + part[3][c];
            float s1 = part[0][c + 1] + part[1][c + 1] + part[2][c + 1] + part[3][c + 1];
            ((float2*)(out + (size_t)n * VDIM))[tid] = make_float2(s0, s1);
        }
        __syncthreads();   // rv/part reuse next token
    }
}

extern "C" void kernel_launch(void* const* d_in, const int* in_sizes, int n_in,
                              void* d_out, int out_size, void* d_ws, size_t ws_size,
                              hipStream_t stream) {
    const float* query  = (const float*)d_in[0];   // 8192*2048
    const float* keys   = (const float*)d_in[1];   // 4096*256
    const float* values = (const float*)d_in[2];   // 262144*512
    float* out = (float*)d_out;

    char* ws = (char*)d_ws;
    u16* kb = (u16*)ws;                            // 2,097,152 B

    k_convert<<<512, 256, 0, stream>>>(keys, kb, (2 * N_HEADS * SUBK * HALFD) / 4);

    k_fused<<<N_TOK / 16, 256, 0, stream>>>(query, kb, keys, values, out);
}

// Round 7
// 412.742 us; speedup vs baseline: 1.1787x; 1.1787x over previous
//
#include <hip/hip_runtime.h>
#include <hip/hip_bf16.h>
#include <math.h>

typedef unsigned short u16;
typedef __attribute__((ext_vector_type(8))) short short8;   // 8 bf16 (4 VGPRs)
typedef __attribute__((ext_vector_type(4))) float f32x4;

#define N_TOK   8192
#define N_HEADS 4
#define KDIM    512
#define HALFD   256
#define VDIM    512
#define SUBK    512
#define NCAND   16

__device__ __forceinline__ u16 f2bf(float f) {
    unsigned u = __float_as_uint(f);
    u += 0x7fffu + ((u >> 16) & 1u);
    return (u16)(u >> 16);
}

__device__ __forceinline__ unsigned med3u(unsigned a, unsigned b, unsigned c) {
    unsigned d;
    asm("v_med3_u32 %0, %1, %2, %3" : "=v"(d) : "v"(a), "v"(b), "v"(c));
    return d;
}

// ---------------- Kernel A: f32 -> bf16 bits (keys only, tiny) ----------------
__global__ void k_convert(const float* __restrict__ in, u16* __restrict__ out, int n4) {
    int i = blockIdx.x * blockDim.x + threadIdx.x;
    int stride = gridDim.x * blockDim.x;
    for (; i < n4; i += stride) {
        float4 v = ((const float4*)in)[i];
        unsigned a = (unsigned)f2bf(v.x) | ((unsigned)f2bf(v.y) << 16);
        unsigned b = (unsigned)f2bf(v.z) | ((unsigned)f2bf(v.w) << 16);
        ((uint2*)out)[i] = make_uint2(a, b);
    }
}

// ------------- Kernel B: bf16 MFMA scores + packed-key exact top-16 -------------
// grid (N/16, HEADS, 2), block 256 (4 waves). Wave w computes s-tiles [8w, 8w+8).
__global__ __launch_bounds__(256) void k_score_topk(
    const float* __restrict__ query,  // [N][2048] f32
    const u16* __restrict__ kb,       // [2][4][512][256] bf16
    int* __restrict__ cand)           // [N][4][2][16]
{
    __shared__ unsigned sc[16 * 513];
    const int nb = blockIdx.x, h = blockIdx.y, half = blockIdx.z;
    const int tid = threadIdx.x;
    const int wave = tid >> 6, l = tid & 63;
    const int lr = l & 15, lk = l >> 4;

    const float* qbase = query + (size_t)(nb * 16 + lr) * (N_HEADS * KDIM)
                       + h * KDIM + half * HALFD + lk * 8;
    short8 a[8];
#pragma unroll
    for (int kf = 0; kf < 8; ++kf) {
        float4 q0 = *(const float4*)(qbase + kf * 32);
        float4 q1 = *(const float4*)(qbase + kf * 32 + 4);
        short8 t;
        t[0] = (short)f2bf(q0.x); t[1] = (short)f2bf(q0.y);
        t[2] = (short)f2bf(q0.z); t[3] = (short)f2bf(q0.w);
        t[4] = (short)f2bf(q1.x); t[5] = (short)f2bf(q1.y);
        t[6] = (short)f2bf(q1.z); t[7] = (short)f2bf(q1.w);
        a[kf] = t;
    }

    const u16* kbase = kb + (size_t)(half * N_HEADS + h) * SUBK * HALFD;
#pragma unroll
    for (int t = 0; t < 8; ++t) {
        const int st = wave * 8 + t;
        const u16* kp = kbase + (size_t)(st * 16 + lr) * HALFD + lk * 8;
        short8 b[8];
#pragma unroll
        for (int kf = 0; kf < 8; ++kf)
            b[kf] = *(const short8*)(kp + kf * 32);
        f32x4 acc = {0.f, 0.f, 0.f, 0.f};
#pragma unroll
        for (int kf = 0; kf < 8; ++kf)
            acc = __builtin_amdgcn_mfma_f32_16x16x32_bf16(a[kf], b[kf], acc, 0, 0, 0);
#pragma unroll
        for (int r = 0; r < 4; ++r) {
            unsigned ub = __float_as_uint(acc[r]);
            unsigned key = ub ^ ((unsigned)((int)ub >> 31) | 0x80000000u);
            key = (key & 0xFFFFFE00u) | (unsigned)(st * 16 + lr);
            sc[(lk * 4 + r) * 513 + st * 16 + lr] = key;
        }
    }
    __syncthreads();

    const int row = tid >> 4, sub = tid & 15;
    unsigned tv[NCAND];
#pragma unroll
    for (int j = 0; j < NCAND; ++j) tv[j] = 0u;
    const int base = row * 513 + sub;
#pragma unroll
    for (int t = 0; t < 32; ++t) {
        unsigned v = sc[base + (t << 4)];
#pragma unroll
        for (int j = NCAND - 1; j >= 1; --j)
            tv[j] = med3u(tv[j - 1], tv[j], v);
        tv[0] = (tv[0] > v) ? tv[0] : v;
    }

    unsigned keep = 0;
#pragma unroll
    for (int r = 0; r < NCAND; ++r) {
        unsigned w = tv[0];
#pragma unroll
        for (int d = 1; d < 16; d <<= 1) {
            unsigned o = __shfl_xor(w, d, 16);
            w = (o > w) ? o : w;
        }
        if (sub == r) keep = w;
        bool pop = (tv[0] == w);
#pragma unroll
        for (int j = 0; j < NCAND - 1; ++j) tv[j] = pop ? tv[j + 1] : tv[j];
        tv[NCAND - 1] = pop ? 0u : tv[NCAND - 1];
    }
    const int n = nb * 16 + row;
    cand[((size_t)n * 8 + (h * 2 + half)) * NCAND + sub] = (int)(keep & 0x1FFu);
}

// ------- Kernel C1: f64 refine + exact 2-stage top-8 + softmax (parallel) -------
// grid = N, block = 256
__global__ __launch_bounds__(256) void k_select(
    const float* __restrict__ query,   // [N][2048]
    const float* __restrict__ keys,    // [2][4][512][256]
    const int* __restrict__ cand,      // [N][8][16]
    int* __restrict__ gout,            // [N][32]
    float* __restrict__ wout)          // [N][32]
{
    __shared__ double rv[8][16];
    __shared__ int    ri[8][16];
    __shared__ double tsv[8][8];
    __shared__ int    tsi[8][8];
    __shared__ double s_comb[32];
    __shared__ int    sgi[32];

    const int n = blockIdx.x;
    const int tid = threadIdx.x;

    // Phase 1: f64 refinement, 2 threads per candidate dot (128 dims each)
    {
        const int dot = tid >> 1, pt = tid & 1;
        const int g = dot >> 4, j = dot & 15;
        const int h = g >> 1, half = g & 1;
        const int sidx = cand[((size_t)n * 8 + g) * NCAND + j];
        const float* qrow = query + (size_t)n * (N_HEADS * KDIM) + h * KDIM + half * HALFD + pt * 128;
        const float* krow = keys + ((size_t)(half * N_HEADS + h) * SUBK + sidx) * HALFD + pt * 128;
        double a0 = 0, a1 = 0, a2 = 0, a3 = 0;
#pragma unroll 8
        for (int d = 0; d < 128; d += 4) {
            float4 qv = *(const float4*)(qrow + d);
            float4 kv = *(const float4*)(krow + d);
            a0 = fma((double)qv.x, (double)kv.x, a0);
            a1 = fma((double)qv.y, (double)kv.y, a1);
            a2 = fma((double)qv.z, (double)kv.z, a2);
            a3 = fma((double)qv.w, (double)kv.w, a3);
        }
        double s = (a0 + a1) + (a2 + a3);
        double o = __shfl_xor(s, 1);
        if (pt == 0) { rv[g][j] = s + o; ri[g][j] = sidx; }
    }
    __syncthreads();

    // Phase 2: top-8 of 16 per group, 16 lanes/group, shfl argmax (tie -> lowest j)
    if (tid < 128) {
        const int g = tid >> 4, j = tid & 15;
        double v = rv[g][j];
        const int idx = ri[g][j];
        for (int r = 0; r < 8; ++r) {
            double bv = v; int bj = j;
#pragma unroll
            for (int d = 1; d < 16; d <<= 1) {
                double ov = __shfl_xor(bv, d, 16);
                int    oj = __shfl_xor(bj, d, 16);
                if (ov > bv || (ov == bv && oj < bj)) { bv = ov; bj = oj; }
            }
            int widx = __shfl(idx, bj, 16);
            if (j == r) { tsv[g][r] = bv; tsi[g][r] = widx; }
            if (j == bj) v = -1e300;
        }
    }
    __syncthreads();

    // Phase 3: per head (one wave each), top-8 of 64 combos (tie -> lowest flat f)
    {
        const int h = tid >> 6, f = tid & 63;
        double c = tsv[h * 2][f >> 3] + tsv[h * 2 + 1][f & 7];
        for (int r = 0; r < 8; ++r) {
            double bv = c; int bf = f;
#pragma unroll
            for (int d = 1; d < 64; d <<= 1) {
                double ov = __shfl_xor(bv, d, 64);
                int    of = __shfl_xor(bf, d, 64);
                if (ov > bv || (ov == bv && of < bf)) { bv = ov; bf = of; }
            }
            if (f == r) {
                s_comb[h * 8 + r] = bv;
                sgi[h * 8 + r] = tsi[h * 2][bf >> 3] * SUBK + tsi[h * 2 + 1][bf & 7];
            }
            if (f == bf) c = -1e300;
        }
    }
    __syncthreads();

    // Phase 4: joint softmax over 32 (parallel, f32 exp after f64 max-subtract)
    if (tid < 32) {
        const int k = tid;
        double s = s_comb[k];
        double m = s;
#pragma unroll
        for (int d = 1; d < 32; d <<= 1) m = fmax(m, __shfl_xor(m, d, 32));
        float e = expf((float)(s - m));
        float sum = e;
#pragma unroll
        for (int d = 1; d < 32; d <<= 1) sum += __shfl_xor(sum, d, 32);
        wout[(size_t)n * 32 + k] = e / sum;
        gout[(size_t)n * 32 + k] = sgi[k];
    }
}

// ------- Kernel C2: SEGMENTED gather — L3-resident 128 MB sweeps -------
// grid = 1024 blocks x 256 threads = 4096 waves, ALL co-resident.
// Each wave owns 2 tokens, accumulators in registers across segments.
// Outer loop: 4 segments of 65536 rows (128 MB) -> active segment fits L3,
// so cross-token duplicate rows (~37%) hit cache instead of HBM.
__global__ __launch_bounds__(256) void k_gather(
    const float* __restrict__ values,  // [262144][512]
    const int* __restrict__ gidx,      // [N][32]
    const float* __restrict__ w,       // [N][32]
    float* __restrict__ out)           // [N][512]
{
    const int wid = blockIdx.x * 4 + (threadIdx.x >> 6);   // 0..4095
    const int lane = threadIdx.x & 63;
    const int t0 = wid * 2, t1 = t0 + 1;

    float wv0 = 0.f, wv1 = 0.f;
    unsigned r0 = 0xFFFFFFFFu, r1 = 0xFFFFFFFFu;   // row ids (invalid seg for lane>=32)
    if (lane < 32) {
        wv0 = w[(size_t)t0 * 32 + lane];
        r0  = (unsigned)gidx[(size_t)t0 * 32 + lane];
        wv1 = w[(size_t)t1 * 32 + lane];
        r1  = (unsigned)gidx[(size_t)t1 * 32 + lane];
    }

    float4 a00 = {0,0,0,0}, a01 = {0,0,0,0};
    float4 a10 = {0,0,0,0}, a11 = {0,0,0,0};

    for (unsigned s = 0; s < 4; ++s) {
        // token 0: rows of this token falling in segment s (ascending k keeps
        // per-token accumulation order fixed regardless of segmentation? No --
        // order differs from unsegmented, but f32 sum order is OUR choice; it
        // is deterministic and within rounding of the f64-weighted reference.)
        for (int k = 0; k < 32; ++k) {
            unsigned o = (unsigned)__shfl((int)r0, k, 64);
            if ((o >> 16) == s) {
                const float* vr = values + (size_t)o * VDIM;
                float4 v0 = *(const float4*)(vr + lane * 4);
                float4 v1 = *(const float4*)(vr + 256 + lane * 4);
                const float wk = __shfl(wv0, k, 64);
                a00.x = fmaf(wk, v0.x, a00.x); a00.y = fmaf(wk, v0.y, a00.y);
                a00.z = fmaf(wk, v0.z, a00.z); a00.w = fmaf(wk, v0.w, a00.w);
                a01.x = fmaf(wk, v1.x, a01.x); a01.y = fmaf(wk, v1.y, a01.y);
                a01.z = fmaf(wk, v1.z, a01.z); a01.w = fmaf(wk, v1.w, a01.w);
            }
        }
        // token 1
        for (int k = 0; k < 32; ++k) {
            unsigned o = (unsigned)__shfl((int)r1, k, 64);
            if ((o >> 16) == s) {
                const float* vr = values + (size_t)o * VDIM;
                float4 v0 = *(const float4*)(vr + lane * 4);
                float4 v1 = *(const float4*)(vr + 256 + lane * 4);
                const float wk = __shfl(wv1, k, 64);
                a10.x = fmaf(wk, v0.x, a10.x); a10.y = fmaf(wk, v0.y, a10.y);
                a10.z = fmaf(wk, v0.z, a10.z); a10.w = fmaf(wk, v0.w, a10.w);
                a11.x = fmaf(wk, v1.x, a11.x); a11.y = fmaf(wk, v1.y, a11.y);
                a11.z = fmaf(wk, v1.z, a11.z); a11.w = fmaf(wk, v1.w, a11.w);
            }
        }
    }

    float* o0 = out + (size_t)t0 * VDIM;
    *(float4*)(o0 + lane * 4) = a00;
    *(float4*)(o0 + 256 + lane * 4) = a01;
    float* o1 = out + (size_t)t1 * VDIM;
    *(float4*)(o1 + lane * 4) = a10;
    *(float4*)(o1 + 256 + lane * 4) = a11;
}

extern "C" void kernel_launch(void* const* d_in, const int* in_sizes, int n_in,
                              void* d_out, int out_size, void* d_ws, size_t ws_size,
                              hipStream_t stream) {
    const float* query  = (const float*)d_in[0];   // 8192*2048
    const float* keys   = (const float*)d_in[1];   // 4096*256
    const float* values = (const float*)d_in[2];   // 262144*512
    float* out = (float*)d_out;

    char* ws = (char*)d_ws;
    u16* kb    = (u16*)ws;                         // 2,097,152 B
    int* cand  = (int*)(ws + 2097152);             // 4,194,304 B
    int* gidxb = (int*)(ws + 2097152 + 4194304);   // 1,048,576 B
    float* wb  = (float*)(ws + 2097152 + 4194304 + 1048576); // 1,048,576 B

    k_convert<<<512, 256, 0, stream>>>(keys, kb, (2 * N_HEADS * SUBK * HALFD) / 4);

    dim3 gB(N_TOK / 16, N_HEADS, 2);
    k_score_topk<<<gB, 256, 0, stream>>>(query, kb, cand);

    k_select<<<N_TOK, 256, 0, stream>>>(query, keys, cand, gidxb, wb);
    k_gather<<<1024, 256, 0, stream>>>(values, gidxb, wb, out);
}

// Round 8
// 387.422 us; speedup vs baseline: 1.2557x; 1.0654x over previous
//
#include <hip/hip_runtime.h>
#include <hip/hip_bf16.h>
#include <math.h>

typedef unsigned short u16;
typedef __attribute__((ext_vector_type(8))) short short8;   // 8 bf16 (4 VGPRs)
typedef __attribute__((ext_vector_type(4))) float f32x4;

#define N_TOK   8192
#define N_HEADS 4
#define KDIM    512
#define HALFD   256
#define VDIM    512
#define SUBK    512
#define NCAND   16

__device__ __forceinline__ u16 f2bf(float f) {
    unsigned u = __float_as_uint(f);
    u += 0x7fffu + ((u >> 16) & 1u);
    return (u16)(u >> 16);
}

__device__ __forceinline__ unsigned med3u(unsigned a, unsigned b, unsigned c) {
    unsigned d;
    asm("v_med3_u32 %0, %1, %2, %3" : "=v"(d) : "v"(a), "v"(b), "v"(c));
    return d;
}

// ---------------- Kernel A: f32 -> bf16 bits (keys only, tiny) ----------------
__global__ void k_convert(const float* __restrict__ in, u16* __restrict__ out, int n4) {
    int i = blockIdx.x * blockDim.x + threadIdx.x;
    int stride = gridDim.x * blockDim.x;
    for (; i < n4; i += stride) {
        float4 v = ((const float4*)in)[i];
        unsigned a = (unsigned)f2bf(v.x) | ((unsigned)f2bf(v.y) << 16);
        unsigned b = (unsigned)f2bf(v.z) | ((unsigned)f2bf(v.w) << 16);
        ((uint2*)out)[i] = make_uint2(a, b);
    }
}

// ------------- Kernel B: bf16 MFMA scores + packed-key exact top-16 -------------
// grid (N/16, HEADS, 2), block 256 (4 waves). Wave w computes s-tiles [8w, 8w+8).
__global__ __launch_bounds__(256) void k_score_topk(
    const float* __restrict__ query,  // [N][2048] f32
    const u16* __restrict__ kb,       // [2][4][512][256] bf16
    int* __restrict__ cand)           // [N][4][2][16]
{
    __shared__ unsigned sc[16 * 513];
    const int nb = blockIdx.x, h = blockIdx.y, half = blockIdx.z;
    const int tid = threadIdx.x;
    const int wave = tid >> 6, l = tid & 63;
    const int lr = l & 15, lk = l >> 4;

    const float* qbase = query + (size_t)(nb * 16 + lr) * (N_HEADS * KDIM)
                       + h * KDIM + half * HALFD + lk * 8;
    short8 a[8];
#pragma unroll
    for (int kf = 0; kf < 8; ++kf) {
        float4 q0 = *(const float4*)(qbase + kf * 32);
        float4 q1 = *(const float4*)(qbase + kf * 32 + 4);
        short8 t;
        t[0] = (short)f2bf(q0.x); t[1] = (short)f2bf(q0.y);
        t[2] = (short)f2bf(q0.z); t[3] = (short)f2bf(q0.w);
        t[4] = (short)f2bf(q1.x); t[5] = (short)f2bf(q1.y);
        t[6] = (short)f2bf(q1.z); t[7] = (short)f2bf(q1.w);
        a[kf] = t;
    }

    const u16* kbase = kb + (size_t)(half * N_HEADS + h) * SUBK * HALFD;
#pragma unroll
    for (int t = 0; t < 8; ++t) {
        const int st = wave * 8 + t;
        const u16* kp = kbase + (size_t)(st * 16 + lr) * HALFD + lk * 8;
        short8 b[8];
#pragma unroll
        for (int kf = 0; kf < 8; ++kf)
            b[kf] = *(const short8*)(kp + kf * 32);
        f32x4 acc = {0.f, 0.f, 0.f, 0.f};
#pragma unroll
        for (int kf = 0; kf < 8; ++kf)
            acc = __builtin_amdgcn_mfma_f32_16x16x32_bf16(a[kf], b[kf], acc, 0, 0, 0);
#pragma unroll
        for (int r = 0; r < 4; ++r) {
            unsigned ub = __float_as_uint(acc[r]);
            unsigned key = ub ^ ((unsigned)((int)ub >> 31) | 0x80000000u);
            key = (key & 0xFFFFFE00u) | (unsigned)(st * 16 + lr);
            sc[(lk * 4 + r) * 513 + st * 16 + lr] = key;
        }
    }
    __syncthreads();

    const int row = tid >> 4, sub = tid & 15;
    unsigned tv[NCAND];
#pragma unroll
    for (int j = 0; j < NCAND; ++j) tv[j] = 0u;
    const int base = row * 513 + sub;
#pragma unroll
    for (int t = 0; t < 32; ++t) {
        unsigned v = sc[base + (t << 4)];
#pragma unroll
        for (int j = NCAND - 1; j >= 1; --j)
            tv[j] = med3u(tv[j - 1], tv[j], v);
        tv[0] = (tv[0] > v) ? tv[0] : v;
    }

    unsigned keep = 0;
#pragma unroll
    for (int r = 0; r < NCAND; ++r) {
        unsigned w = tv[0];
#pragma unroll
        for (int d = 1; d < 16; d <<= 1) {
            unsigned o = __shfl_xor(w, d, 16);
            w = (o > w) ? o : w;
        }
        if (sub == r) keep = w;
        bool pop = (tv[0] == w);
#pragma unroll
        for (int j = 0; j < NCAND - 1; ++j) tv[j] = pop ? tv[j + 1] : tv[j];
        tv[NCAND - 1] = pop ? 0u : tv[NCAND - 1];
    }
    const int n = nb * 16 + row;
    cand[((size_t)n * 8 + (h * 2 + half)) * NCAND + sub] = (int)(keep & 0x1FFu);
}

// --- Kernel C: f64 refine + exact 2-stage top-8 + softmax + deep row-per-wave gather ---
// grid = N, block = 256 (4 waves)
__global__ __launch_bounds__(256) void k_select_gather(
    const float* __restrict__ query,   // [N][2048]
    const float* __restrict__ keys,    // [2][4][512][256]
    const float* __restrict__ values,  // [262144][512]
    const int* __restrict__ cand,      // [N][8][16]
    float* __restrict__ out)           // [N][512]
{
    __shared__ double rv[8][16];
    __shared__ int    ri[8][16];
    __shared__ double tsv[8][8];
    __shared__ int    tsi[8][8];
    __shared__ double s_comb[32];
    __shared__ int    sgi[32];
    __shared__ float  wsm[32];
    __shared__ float  part[4][512];    // cross-wave gather partials (8 KB)

    const int n = blockIdx.x;
    const int tid = threadIdx.x;

    // Phase 1: f64 refinement, 2 threads per candidate dot (128 dims each)
    {
        const int dot = tid >> 1, pt = tid & 1;
        const int g = dot >> 4, j = dot & 15;
        const int h = g >> 1, half = g & 1;
        const int sidx = cand[((size_t)n * 8 + g) * NCAND + j];
        const float* qrow = query + (size_t)n * (N_HEADS * KDIM) + h * KDIM + half * HALFD + pt * 128;
        const float* krow = keys + ((size_t)(half * N_HEADS + h) * SUBK + sidx) * HALFD + pt * 128;
        double a0 = 0, a1 = 0, a2 = 0, a3 = 0;
#pragma unroll 8
        for (int d = 0; d < 128; d += 4) {
            float4 qv = *(const float4*)(qrow + d);
            float4 kv = *(const float4*)(krow + d);
            a0 = fma((double)qv.x, (double)kv.x, a0);
            a1 = fma((double)qv.y, (double)kv.y, a1);
            a2 = fma((double)qv.z, (double)kv.z, a2);
            a3 = fma((double)qv.w, (double)kv.w, a3);
        }
        double s = (a0 + a1) + (a2 + a3);
        double o = __shfl_xor(s, 1);
        if (pt == 0) { rv[g][j] = s + o; ri[g][j] = sidx; }
    }
    __syncthreads();

    // Phase 2: top-8 of 16 per group, 16 lanes/group, shfl argmax (tie -> lowest j)
    if (tid < 128) {
        const int g = tid >> 4, j = tid & 15;
        double v = rv[g][j];
        const int idx = ri[g][j];
        for (int r = 0; r < 8; ++r) {
            double bv = v; int bj = j;
#pragma unroll
            for (int d = 1; d < 16; d <<= 1) {
                double ov = __shfl_xor(bv, d, 16);
                int    oj = __shfl_xor(bj, d, 16);
                if (ov > bv || (ov == bv && oj < bj)) { bv = ov; bj = oj; }
            }
            int widx = __shfl(idx, bj, 16);
            if (j == r) { tsv[g][r] = bv; tsi[g][r] = widx; }
            if (j == bj) v = -1e300;
        }
    }
    __syncthreads();

    // Phase 3: per head (one wave each), top-8 of 64 combos (tie -> lowest flat f)
    {
        const int h = tid >> 6, f = tid & 63;
        double c = tsv[h * 2][f >> 3] + tsv[h * 2 + 1][f & 7];
        for (int r = 0; r < 8; ++r) {
            double bv = c; int bf = f;
#pragma unroll
            for (int d = 1; d < 64; d <<= 1) {
                double ov = __shfl_xor(bv, d, 64);
                int    of = __shfl_xor(bf, d, 64);
                if (ov > bv || (ov == bv && of < bf)) { bv = ov; bf = of; }
            }
            if (f == r) {
                s_comb[h * 8 + r] = bv;
                sgi[h * 8 + r] = tsi[h * 2][bf >> 3] * SUBK + tsi[h * 2 + 1][bf & 7];
            }
            if (f == bf) c = -1e300;
        }
    }
    __syncthreads();

    // Phase 4: joint softmax over 32 (parallel, f32 exp after f64 max-subtract)
    if (tid < 32) {
        const int k = tid;
        double s = s_comb[k];
        double m = s;
#pragma unroll
        for (int d = 1; d < 32; d <<= 1) m = fmax(m, __shfl_xor(m, d, 32));
        float e = expf((float)(s - m));
        float sum = e;
#pragma unroll
        for (int d = 1; d < 32; d <<= 1) sum += __shfl_xor(sum, d, 32);
        wsm[k] = e / sum;
    }
    __syncthreads();

    // Phase 5: gather — wave w reads rows 8w..8w+7 (2 KB each, as 2x 1 KB
    // dwordx4 bursts). ALL 16 loads issued before any FMA: 16 vmem ops in
    // flight per wave, no exposed second-batch latency at the token tail.
    {
        const int w = tid >> 6, lane = tid & 63;
        float4 v0[8], v1[8];
#pragma unroll
        for (int r = 0; r < 8; ++r) {
            const float* vr = values + (size_t)sgi[w * 8 + r] * VDIM;
            v0[r] = *(const float4*)(vr + lane * 4);
            v1[r] = *(const float4*)(vr + 256 + lane * 4);
        }
        float4 acc0 = {0.f, 0.f, 0.f, 0.f};
        float4 acc1 = {0.f, 0.f, 0.f, 0.f};
#pragma unroll
        for (int r = 0; r < 8; ++r) {
            const float wk = wsm[w * 8 + r];
            acc0.x = fmaf(wk, v0[r].x, acc0.x);
            acc0.y = fmaf(wk, v0[r].y, acc0.y);
            acc0.z = fmaf(wk, v0[r].z, acc0.z);
            acc0.w = fmaf(wk, v0[r].w, acc0.w);
            acc1.x = fmaf(wk, v1[r].x, acc1.x);
            acc1.y = fmaf(wk, v1[r].y, acc1.y);
            acc1.z = fmaf(wk, v1[r].z, acc1.z);
            acc1.w = fmaf(wk, v1[r].w, acc1.w);
        }
        *(float4*)(&part[w][lane * 4]) = acc0;
        *(float4*)(&part[w][256 + lane * 4]) = acc1;
    }
    __syncthreads();

    // Cross-wave reduction: thread t sums 4 partials for cols [2t, 2t+1]
    {
        const int c = tid * 2;
        float s0 = part[0][c]     + part[1][c]     + part[2][c]     + part[3][c];
        float s1 = part[0][c + 1] + part[1][c + 1] + part[2][c + 1] + part[3][c + 1];
        ((float2*)(out + (size_t)n * VDIM))[tid] = make_float2(s0, s1);
    }
}

extern "C" void kernel_launch(void* const* d_in, const int* in_sizes, int n_in,
                              void* d_out, int out_size, void* d_ws, size_t ws_size,
                              hipStream_t stream) {
    const float* query  = (const float*)d_in[0];   // 8192*2048
    const float* keys   = (const float*)d_in[1];   // 4096*256
    const float* values = (const float*)d_in[2];   // 262144*512
    float* out = (float*)d_out;

    char* ws = (char*)d_ws;
    u16* kb   = (u16*)ws;                          // 2,097,152 B
    int* cand = (int*)(ws + 2097152);              // 4,194,304 B

    k_convert<<<512, 256, 0, stream>>>(keys, kb, (2 * N_HEADS * SUBK * HALFD) / 4);

    dim3 gB(N_TOK / 16, N_HEADS, 2);
    k_score_topk<<<gB, 256, 0, stream>>>(query, kb, cand);

    k_select_gather<<<N_TOK, 256, 0, stream>>>(query, keys, values, cand, out);
}